// Round 3
// baseline (267.762 us; speedup 1.0000x reference)
//
#include <hip/hip_runtime.h>

// Problem constants
#define TT_ISTRIDE 672          // transposed: per-i stride = 8 r * 84 padded j
#define TT_ELEMS (4 * 81 * 672) // 217728 floats

// Transpose T[a][q0][q1][q2][q3][r] (flat a*52488 + i*648 + j*8 + r, i=q0*9+q1, j=q2*9+q3)
//        -> Tt[a][i][r][84]  where the 84 j-columns are THREE 28-wide thirds:
//        col = jt*28 + (j - jt*27), jt = j/27; slot 27 of each third is zero pad.
__global__ void t_transpose(const float* __restrict__ T, float* __restrict__ Tt) {
    int idx = blockIdx.x * 256 + threadIdx.x;
    if (idx >= TT_ELEMS) return;
    int col  = idx % 84;
    int t1   = idx / 84;
    int r    = t1 & 7;
    int rest = t1 / 8;  // a*81 + i
    int jt   = col / 28;
    int kk   = col - jt * 28;      // 0..27; 27 = pad
    Tt[idx] = (kk < 27) ? T[rest * 648 + (jt * 27 + kk) * 8 + r] : 0.0f;
}

// One block: 512 threads = 8 waves, (64 batches) x (one aggregator a).
// grid = 512 blocks -> 2 blocks/CU (LDS 57KB). T loads are VECTOR loads with
// wave-identical addresses (L1 broadcast) so vmcnt pipelining hides latency
// (scalar s_load path forced lgkmcnt(0) drains -> 37% VALUBusy in round 2).
__global__ __launch_bounds__(512, 4) void hosvd_fused(
    const float* __restrict__ nh,   // [8192][4][256]
    const float* __restrict__ U,    // [4][4][256][8]
    const float* __restrict__ bi,   // [4][4][1][8]
    const float* __restrict__ Uo,   // [4][8][256]
    const float* __restrict__ bo,   // [4][1][256]
    const float* __restrict__ Tt,   // transposed T in ws
    float* __restrict__ out) {      // [8192][1024]
    __shared__ float u_lds[4 * 256 * 8];   // 32 KB: U[c][a=blk][h][r]
    __shared__ float uo_lds[8 * 256];      // 8 KB:  U_out[a][r][h]
    __shared__ float h_t[36][64];          // 9 KB:  h_t[c*9+q][batch] (lane-stride-1: no conflicts)
    __shared__ float red_t[24][64];        // 6 KB:  red_t[sweep][batch]
    __shared__ float ris_s[64][8];         // 2 KB:  ris[batch][r] for phase C b128 broadcasts

    const int t    = threadIdx.x;
    const int lane = t & 63;
    const int widr = t >> 6;
    const int a    = blockIdx.x & 3;
    const int b0   = (blockIdx.x >> 2) << 6;

    // ---- stage U[., a, ., .] and Uo[a] into LDS (coalesced)
    for (int idx = t; idx < 8192; idx += 512) {
        int c   = idx >> 11;
        int rem = idx & 2047;              // h*8 + r
        u_lds[idx] = U[((c * 4 + a) << 11) + rem];
    }
    for (int idx = t; idx < 2048; idx += 512)
        uo_lds[idx] = Uo[(a << 11) + idx];
    __syncthreads();

    // ---- phase X: x[b][c][r] = nh[b,c,:] . U[c,a,:,r] + bi[c,a,r]  -> h_t
    {
        const int c  = widr >> 1;
        const int r0 = (widr & 1) << 2;
        const float* nhp   = nh + (size_t)(b0 + lane) * 1024 + (size_t)c * 256;
        const float* ubase = u_lds + (c << 11) + r0;
        float4 acc = make_float4(0.f, 0.f, 0.f, 0.f);
        #pragma unroll 4
        for (int h = 0; h < 256; h += 4) {
            float4 v  = *(const float4*)(nhp + h);
            float4 u0 = *(const float4*)(ubase + ((h + 0) << 3));
            float4 u1 = *(const float4*)(ubase + ((h + 1) << 3));
            float4 u2 = *(const float4*)(ubase + ((h + 2) << 3));
            float4 u3 = *(const float4*)(ubase + ((h + 3) << 3));
            acc.x = fmaf(v.x, u0.x, acc.x); acc.y = fmaf(v.x, u0.y, acc.y);
            acc.z = fmaf(v.x, u0.z, acc.z); acc.w = fmaf(v.x, u0.w, acc.w);
            acc.x = fmaf(v.y, u1.x, acc.x); acc.y = fmaf(v.y, u1.y, acc.y);
            acc.z = fmaf(v.y, u1.z, acc.z); acc.w = fmaf(v.y, u1.w, acc.w);
            acc.x = fmaf(v.z, u2.x, acc.x); acc.y = fmaf(v.z, u2.y, acc.y);
            acc.z = fmaf(v.z, u2.z, acc.z); acc.w = fmaf(v.z, u2.w, acc.w);
            acc.x = fmaf(v.w, u3.x, acc.x); acc.y = fmaf(v.w, u3.y, acc.y);
            acc.z = fmaf(v.w, u3.z, acc.z); acc.w = fmaf(v.w, u3.w, acc.w);
        }
        const float4 bb4 = *(const float4*)&bi[((c * 4 + a) << 3) + r0];
        h_t[c * 9 + r0 + 0][lane] = acc.x + bb4.x;
        h_t[c * 9 + r0 + 1][lane] = acc.y + bb4.y;
        h_t[c * 9 + r0 + 2][lane] = acc.z + bb4.z;
        h_t[c * 9 + r0 + 3][lane] = acc.w + bb4.w;
        if (r0) h_t[c * 9 + 8][lane] = 1.0f;   // augmented 1
    }
    __syncthreads();

    // ---- phase B: ris[r] = sum_{i,j} h0[q0]h1[q1] h2[q2]h3[q3] T[i,j,r]
    // 24 sweeps of 27 j's (one r each); 8 waves x 3 sweeps.
    {
        float h0v[9], h1v[9], h3v[9];
        #pragma unroll
        for (int q = 0; q < 9; ++q) {
            h0v[q] = h_t[q][lane];
            h1v[q] = h_t[9 + q][lane];
            h3v[q] = h_t[27 + q][lane];
        }
        const float* Tw = Tt + (size_t)(a * 81) * TT_ISTRIDE;
        #pragma unroll 1
        for (int ss = 0; ss < 3; ++ss) {
            const int sg = widr * 3 + ss;    // wave-uniform in fact, vector in IR
            const int r  = sg & 7;
            const int jt = sg >> 3;
            const float* tb = Tw + r * 84 + jt * 28;   // 16B-aligned third
            float z[27];
            #pragma unroll
            for (int k = 0; k < 27; ++k) z[k] = 0.0f;
            #pragma unroll 1
            for (int q0 = 0; q0 < 9; ++q0) {
                const float h0q = h0v[q0];
                #pragma unroll
                for (int q1 = 0; q1 < 9; ++q1) {
                    const float4* tp = (const float4*)(tb + (q0 * 9 + q1) * TT_ISTRIDE);
                    const float4 t0 = tp[0];
                    const float4 t1 = tp[1];
                    const float4 t2 = tp[2];
                    const float4 t3 = tp[3];
                    const float4 t4 = tp[4];
                    const float4 t5 = tp[5];
                    const float4 t6 = tp[6];
                    const float w = h0q * h1v[q1];
                    z[ 0] = fmaf(w, t0.x, z[ 0]); z[ 1] = fmaf(w, t0.y, z[ 1]);
                    z[ 2] = fmaf(w, t0.z, z[ 2]); z[ 3] = fmaf(w, t0.w, z[ 3]);
                    z[ 4] = fmaf(w, t1.x, z[ 4]); z[ 5] = fmaf(w, t1.y, z[ 5]);
                    z[ 6] = fmaf(w, t1.z, z[ 6]); z[ 7] = fmaf(w, t1.w, z[ 7]);
                    z[ 8] = fmaf(w, t2.x, z[ 8]); z[ 9] = fmaf(w, t2.y, z[ 9]);
                    z[10] = fmaf(w, t2.z, z[10]); z[11] = fmaf(w, t2.w, z[11]);
                    z[12] = fmaf(w, t3.x, z[12]); z[13] = fmaf(w, t3.y, z[13]);
                    z[14] = fmaf(w, t3.z, z[14]); z[15] = fmaf(w, t3.w, z[15]);
                    z[16] = fmaf(w, t4.x, z[16]); z[17] = fmaf(w, t4.y, z[17]);
                    z[18] = fmaf(w, t4.z, z[18]); z[19] = fmaf(w, t4.w, z[19]);
                    z[20] = fmaf(w, t5.x, z[20]); z[21] = fmaf(w, t5.y, z[21]);
                    z[22] = fmaf(w, t5.z, z[22]); z[23] = fmaf(w, t5.w, z[23]);
                    z[24] = fmaf(w, t6.x, z[24]); z[25] = fmaf(w, t6.y, z[25]);
                    z[26] = fmaf(w, t6.z, z[26]);
                }
            }
            // fold j: j = jt*27 + k, q2 = 3*jt + k/9, q3 = k%9
            const float h2a = h_t[18 + jt * 3 + 0][lane];
            const float h2b = h_t[18 + jt * 3 + 1][lane];
            const float h2c = h_t[18 + jt * 3 + 2][lane];
            float d0 = 0.f, d1 = 0.f, d2 = 0.f;
            #pragma unroll
            for (int k = 0; k < 9; ++k) {
                d0 = fmaf(h3v[k], z[k],      d0);
                d1 = fmaf(h3v[k], z[9 + k],  d1);
                d2 = fmaf(h3v[k], z[18 + k], d2);
            }
            red_t[sg][lane] = fmaf(h2a, d0, fmaf(h2b, d1, h2c * d2));
        }
    }
    __syncthreads();

    // ---- reduce 3 jt-partials -> ris_s[b][r]
    // thread (b,r) reads rows {r, 8+r, 16+r} at column b; no cross-thread hazard.
    {
        const int b = t >> 3, r = t & 7;
        ris_s[b][r] = red_t[r][b] + red_t[8 + r][b] + red_t[16 + r][b];
    }
    __syncthreads();

    // ---- phase C: out[b, a*256+h] = sum_r ris[b][r]*Uo[a][r][h] + bo[a][h]
    {
        const int h  = t & 255;
        const int bh = t >> 8;   // 0..1
        const float bov = bo[(a << 8) + h];
        const float u0 = uo_lds[h],            u1 = uo_lds[256 + h];
        const float u2 = uo_lds[512 + h],      u3 = uo_lds[768 + h];
        const float u4 = uo_lds[1024 + h],     u5 = uo_lds[1280 + h];
        const float u6 = uo_lds[1536 + h],     u7 = uo_lds[1792 + h];
        float* op = out + (size_t)(b0 + (bh << 5)) * 1024 + (a << 8) + h;
        #pragma unroll 4
        for (int bb = 0; bb < 32; ++bb) {
            const int bidx = (bh << 5) + bb;
            const float4 rlo = *(const float4*)&ris_s[bidx][0];
            const float4 rhi = *(const float4*)&ris_s[bidx][4];
            float v = bov;
            v = fmaf(rlo.x, u0, v); v = fmaf(rlo.y, u1, v);
            v = fmaf(rlo.z, u2, v); v = fmaf(rlo.w, u3, v);
            v = fmaf(rhi.x, u4, v); v = fmaf(rhi.y, u5, v);
            v = fmaf(rhi.z, u6, v); v = fmaf(rhi.w, u7, v);
            op[(size_t)bb * 1024] = v;
        }
    }
}

extern "C" void kernel_launch(void* const* d_in, const int* in_sizes, int n_in,
                              void* d_out, int out_size, void* d_ws, size_t ws_size,
                              hipStream_t stream) {
    (void)in_sizes; (void)n_in; (void)out_size; (void)ws_size;
    const float* nh = (const float*)d_in[0];
    const float* U  = (const float*)d_in[1];
    const float* bi = (const float*)d_in[2];
    const float* Uo = (const float*)d_in[3];
    const float* bo = (const float*)d_in[4];
    const float* T  = (const float*)d_in[5];
    float* outp = (float*)d_out;
    float* Tt   = (float*)d_ws;   // 217728*4 = 870,912 bytes

    t_transpose<<<(TT_ELEMS + 255) / 256, 256, 0, stream>>>(T, Tt);
    hosvd_fused<<<512, 512, 0, stream>>>(nh, U, bi, Uo, bo, Tt, outp);
}

// Round 4
// 100.283 us; speedup vs baseline: 2.6701x; 2.6701x over previous
//
#include <hip/hip_runtime.h>

// Problem constants
#define TT_ISTRIDE 672          // transposed: per-i stride = 8 r * 84 padded j
#define TT_ELEMS (4 * 81 * 672) // 217728 floats
#define CHUNK_FLOATS (9 * 672)  // one i-chunk (9 i's) = 6048 floats = 24.2 KB
#define CHUNK_F4 (CHUNK_FLOATS / 4)  // 1512 float4s

// Transpose T[a][q0][q1][q2][q3][r] (flat a*52488 + i*648 + j*8 + r, i=q0*9+q1, j=q2*9+q3)
//        -> Tt[a][i][r][84]  where the 84 j-columns are THREE 28-wide thirds:
//        col = jt*28 + (j - jt*27), jt = j/27; slot 27 of each third is zero pad.
__global__ void t_transpose(const float* __restrict__ T, float* __restrict__ Tt) {
    int idx = blockIdx.x * 256 + threadIdx.x;
    if (idx >= TT_ELEMS) return;
    int col  = idx % 84;
    int t1   = idx / 84;
    int r    = t1 & 7;
    int rest = t1 / 8;  // a*81 + i
    int jt   = col / 28;
    int kk   = col - jt * 28;      // 0..27; 27 = pad
    Tt[idx] = (kk < 27) ? T[rest * 648 + (jt * 27 + kk) * 8 + r] : 0.0f;
}

// global -> LDS direct (no VGPR round trip); dest is linear: uniform base + lane*16
#define GLL(gsrc, ldst) __builtin_amdgcn_global_load_lds( \
    (const __attribute__((address_space(1))) void*)(gsrc), \
    (__attribute__((address_space(3))) void*)(ldst), 16, 0, 0)

// One block: 512 threads = 8 waves, (64 batches) x (one aggregator a).
// Phase B: T staged into LDS in 9 double-buffered chunks (chunk c = i in [9c,9c+9), q0=c).
// Wave w owns r=w; per i it computes the full j-dot via 9 group-dots with h3,
// folds with h2, accumulates A with weight h0[c]*h1[q1]. A == ris[lane][w] directly.
__global__ __launch_bounds__(512, 4) void hosvd_fused(
    const float* __restrict__ nh,   // [8192][4][256]
    const float* __restrict__ U,    // [4][4][256][8]
    const float* __restrict__ bi,   // [4][4][1][8]
    const float* __restrict__ Uo,   // [4][8][256]
    const float* __restrict__ bo,   // [4][1][256]
    const float* __restrict__ Tt,   // transposed T in ws
    float* __restrict__ out) {      // [8192][1024]
    __shared__ union {
        float u[4 * 256 * 8];            // 32 KB  (phase X only)
        float tc[2][CHUNK_FLOATS];       // 48.4 KB (phase B double buffer)
    } sm;
    __shared__ float uo_lds[8 * 256];    // 8 KB:  U_out[a][r][h]
    __shared__ float h_t[36][64];        // 9 KB:  h_t[c*9+q][batch], lane-stride-1
    __shared__ float ris_s[64][8];       // 2 KB:  ris[batch][r]

    const int t    = threadIdx.x;
    const int lane = t & 63;
    const int widr = t >> 6;
    // bijective XCD grouping (512 = 8*64): the 4 a-blocks of one batch-group land
    // on one XCD -> nh rows L2-shared, fetched ~once.
    const int wg   = (blockIdx.x & 7) * 64 + (blockIdx.x >> 3);
    const int a    = wg & 3;
    const int b0   = (wg >> 2) << 6;

    // ---- stage U[., a, ., .] and Uo[a] into LDS (coalesced)
    for (int idx = t; idx < 8192; idx += 512) {
        int c   = idx >> 11;
        int rem = idx & 2047;              // h*8 + r
        sm.u[idx] = U[((c * 4 + a) << 11) + rem];
    }
    for (int idx = t; idx < 2048; idx += 512)
        uo_lds[idx] = Uo[(a << 11) + idx];
    __syncthreads();

    // ---- phase X: x[b][c][r] = nh[b,c,:] . U[c,a,:,r] + bi[c,a,r]  -> h_t
    {
        const int c  = widr >> 1;
        const int r0 = (widr & 1) << 2;
        const float* nhp   = nh + (size_t)(b0 + lane) * 1024 + (size_t)c * 256;
        const float* ubase = sm.u + (c << 11) + r0;
        float4 acc = make_float4(0.f, 0.f, 0.f, 0.f);
        #pragma unroll 4
        for (int h = 0; h < 256; h += 4) {
            float4 v  = *(const float4*)(nhp + h);
            float4 u0 = *(const float4*)(ubase + ((h + 0) << 3));
            float4 u1 = *(const float4*)(ubase + ((h + 1) << 3));
            float4 u2 = *(const float4*)(ubase + ((h + 2) << 3));
            float4 u3 = *(const float4*)(ubase + ((h + 3) << 3));
            acc.x = fmaf(v.x, u0.x, acc.x); acc.y = fmaf(v.x, u0.y, acc.y);
            acc.z = fmaf(v.x, u0.z, acc.z); acc.w = fmaf(v.x, u0.w, acc.w);
            acc.x = fmaf(v.y, u1.x, acc.x); acc.y = fmaf(v.y, u1.y, acc.y);
            acc.z = fmaf(v.y, u1.z, acc.z); acc.w = fmaf(v.y, u1.w, acc.w);
            acc.x = fmaf(v.z, u2.x, acc.x); acc.y = fmaf(v.z, u2.y, acc.y);
            acc.z = fmaf(v.z, u2.z, acc.z); acc.w = fmaf(v.z, u2.w, acc.w);
            acc.x = fmaf(v.w, u3.x, acc.x); acc.y = fmaf(v.w, u3.y, acc.y);
            acc.z = fmaf(v.w, u3.z, acc.z); acc.w = fmaf(v.w, u3.w, acc.w);
        }
        const float4 bb4 = *(const float4*)&bi[((c * 4 + a) << 3) + r0];
        h_t[c * 9 + r0 + 0][lane] = acc.x + bb4.x;
        h_t[c * 9 + r0 + 1][lane] = acc.y + bb4.y;
        h_t[c * 9 + r0 + 2][lane] = acc.z + bb4.z;
        h_t[c * 9 + r0 + 3][lane] = acc.w + bb4.w;
        if (r0) h_t[c * 9 + 8][lane] = 1.0f;   // augmented 1
    }
    __syncthreads();   // also ensures all sm.u reads done before DMA overwrites it

    // ---- phase B
    {
        float h0v[9], h1v[9], h2v[9], h3v[9];
        #pragma unroll
        for (int q = 0; q < 9; ++q) {
            h0v[q] = h_t[q][lane];
            h1v[q] = h_t[9 + q][lane];
            h2v[q] = h_t[18 + q][lane];
            h3v[q] = h_t[27 + q][lane];
        }
        const float* Tw = Tt + (size_t)(a * 81) * TT_ISTRIDE;
        float A = 0.0f;

        // prologue: stage chunk 0 into buffer 0
        {
            const float* s = Tw;
            float* d = sm.tc[0];
            GLL(s + 4 * t, d + 4 * t);
            GLL(s + 4 * (512 + t), d + 4 * (512 + t));
            if (t < CHUNK_F4 - 1024) GLL(s + 4 * (1024 + t), d + 4 * (1024 + t));
        }

        #pragma unroll 1
        for (int c = 0; c < 9; ++c) {
            if (c < 8) {
                const float* s = Tw + (size_t)(c + 1) * CHUNK_FLOATS;
                float* d = sm.tc[(c + 1) & 1];
                GLL(s + 4 * t, d + 4 * t);
                GLL(s + 4 * (512 + t), d + 4 * (512 + t));
                if (t < CHUNK_F4 - 1024) GLL(s + 4 * (1024 + t), d + 4 * (1024 + t));
                asm volatile("s_waitcnt vmcnt(3)" ::: "memory");  // this wave's chunk-c loads done
            } else {
                asm volatile("s_waitcnt vmcnt(0)" ::: "memory");
            }
            __builtin_amdgcn_s_barrier();          // all waves' chunk-c DMA landed
            asm volatile("" ::: "memory");         // fence: no LDS reads hoist above barrier

            const float* tcp = sm.tc[c & 1] + widr * 84;   // r = widr
            const float h0c  = h0v[c];                      // q0 == chunk index
            #pragma unroll 1
            for (int q1 = 0; q1 < 9; ++q1) {
                const float* tp = tcp + q1 * TT_ISTRIDE;    // i_local = q1
                float dd = 0.0f;
                #pragma unroll
                for (int jt = 0; jt < 3; ++jt) {
                    float s[28];
                    #pragma unroll
                    for (int m = 0; m < 7; ++m)
                        *(float4*)(s + 4 * m) = *(const float4*)(tp + jt * 28 + 4 * m);
                    float e0 = 0.f, e1 = 0.f, e2 = 0.f;
                    #pragma unroll
                    for (int m = 0; m < 9; ++m) {
                        e0 = fmaf(s[m],      h3v[m], e0);
                        e1 = fmaf(s[9 + m],  h3v[m], e1);
                        e2 = fmaf(s[18 + m], h3v[m], e2);
                    }
                    dd += fmaf(h2v[3 * jt + 2], e2,
                           fmaf(h2v[3 * jt + 1], e1, h2v[3 * jt] * e0));
                }
                A = fmaf(h0c * h1v[q1], dd, A);
            }
            asm volatile("" ::: "memory");         // fence: no LDS reads sink below barrier
            __builtin_amdgcn_s_barrier();          // safe to overwrite buffer (c+2)&1 next iter
        }
        ris_s[lane][widr] = A;                     // 512 threads -> 512 slots, direct
    }
    __syncthreads();

    // ---- phase C: out[b, a*256+h] = sum_r ris[b][r]*Uo[a][r][h] + bo[a][h]
    {
        const int h  = t & 255;
        const int bh = t >> 8;   // 0..1
        const float bov = bo[(a << 8) + h];
        const float u0 = uo_lds[h],            u1 = uo_lds[256 + h];
        const float u2 = uo_lds[512 + h],      u3 = uo_lds[768 + h];
        const float u4 = uo_lds[1024 + h],     u5 = uo_lds[1280 + h];
        const float u6 = uo_lds[1536 + h],     u7 = uo_lds[1792 + h];
        float* op = out + (size_t)(b0 + (bh << 5)) * 1024 + (a << 8) + h;
        #pragma unroll 4
        for (int bb = 0; bb < 32; ++bb) {
            const int bidx = (bh << 5) + bb;
            const float4 rlo = *(const float4*)&ris_s[bidx][0];
            const float4 rhi = *(const float4*)&ris_s[bidx][4];
            float v = bov;
            v = fmaf(rlo.x, u0, v); v = fmaf(rlo.y, u1, v);
            v = fmaf(rlo.z, u2, v); v = fmaf(rlo.w, u3, v);
            v = fmaf(rhi.x, u4, v); v = fmaf(rhi.y, u5, v);
            v = fmaf(rhi.z, u6, v); v = fmaf(rhi.w, u7, v);
            op[(size_t)bb * 1024] = v;
        }
    }
}

extern "C" void kernel_launch(void* const* d_in, const int* in_sizes, int n_in,
                              void* d_out, int out_size, void* d_ws, size_t ws_size,
                              hipStream_t stream) {
    (void)in_sizes; (void)n_in; (void)out_size; (void)ws_size;
    const float* nh = (const float*)d_in[0];
    const float* U  = (const float*)d_in[1];
    const float* bi = (const float*)d_in[2];
    const float* Uo = (const float*)d_in[3];
    const float* bo = (const float*)d_in[4];
    const float* T  = (const float*)d_in[5];
    float* outp = (float*)d_out;
    float* Tt   = (float*)d_ws;   // 217728*4 = 870,912 bytes

    t_transpose<<<(TT_ELEMS + 255) / 256, 256, 0, stream>>>(T, Tt);
    hosvd_fused<<<512, 512, 0, stream>>>(nh, U, bi, Uo, bo, Tt, outp);
}

// Round 5
// 96.545 us; speedup vs baseline: 2.7734x; 1.0387x over previous
//
#include <hip/hip_runtime.h>

// Problem constants
#define TT_ISTRIDE 672          // transposed: per-i stride = 8 r * 84 padded j
#define TT_ELEMS (4 * 81 * 672) // 217728 floats
#define CHUNK_FLOATS (9 * 672)  // one i-chunk (9 i's) = 6048 floats = 24.2 KB
#define CHUNK_F4 (CHUNK_FLOATS / 4)  // 1512 float4s

// Transpose T[a][q0][q1][q2][q3][r] -> Tt[a][i][r][84], j in three 28-wide thirds
// col = jt*28 + (j - jt*27); slot 27 of each third is zero pad (16B-aligned thirds).
__global__ void t_transpose(const float* __restrict__ T, float* __restrict__ Tt) {
    int idx = blockIdx.x * 256 + threadIdx.x;
    if (idx >= TT_ELEMS) return;
    int col  = idx % 84;
    int t1   = idx / 84;
    int r    = t1 & 7;
    int rest = t1 / 8;  // a*81 + i
    int jt   = col / 28;
    int kk   = col - jt * 28;      // 0..27; 27 = pad
    Tt[idx] = (kk < 27) ? T[rest * 648 + (jt * 27 + kk) * 8 + r] : 0.0f;
}

// global -> LDS direct; LDS dest is wave-uniform base + lane*16 (linear), matches 4*t
#define GLL(gsrc, ldst) __builtin_amdgcn_global_load_lds( \
    (const __attribute__((address_space(1))) void*)(gsrc), \
    (__attribute__((address_space(3))) void*)(ldst), 16, 0, 0)

// 512 threads = 8 waves; 128 batches x 1 aggregator per block; grid 256 = 1 block/CU.
// Each lane owns TWO batches (lane, lane+64): halves the broadcast-DS per FMA
// (DS pipe is per-CU; uniform ds_read_b128 still ~8cy writeback -> was the r4 limit).
// launch_bounds(512,2): VGPR cap 256 so the 72 h-values live in registers.
__global__ __launch_bounds__(512, 2) void hosvd_fused(
    const float* __restrict__ nh,   // [8192][4][256]
    const float* __restrict__ U,    // [4][4][256][8]
    const float* __restrict__ bi,   // [4][4][1][8]
    const float* __restrict__ Uo,   // [4][8][256]
    const float* __restrict__ bo,   // [4][1][256]
    const float* __restrict__ Tt,   // transposed T in ws
    float* __restrict__ out) {      // [8192][1024]
    __shared__ union {
        float u[4 * 256 * 8];            // 32 KB  (phase X only)
        float tc[2][CHUNK_FLOATS];       // 48.4 KB (phase B double buffer)
    } sm;
    __shared__ float uo_lds[8 * 256];    // 8 KB
    __shared__ float h_t[36][128];       // 18 KB: h_t[c*9+q][batch], lane-stride-1
    __shared__ float ris_s[128][8];      // 4 KB

    const int t    = threadIdx.x;
    const int lane = t & 63;
    const int widr = t >> 6;
    // XCD grouping: grid 256 = 8 XCD x 32; 4 a-blocks of a batch-group share an XCD L2
    const int wg   = (blockIdx.x & 7) * 32 + (blockIdx.x >> 3);
    const int a    = wg & 3;
    const int b0   = (wg >> 2) << 7;     // 128 batches per block

    // ---- stage U[., a, ., .] and Uo[a] into LDS
    for (int idx = t; idx < 8192; idx += 512) {
        int c   = idx >> 11;
        int rem = idx & 2047;
        sm.u[idx] = U[((c * 4 + a) << 11) + rem];
    }
    for (int idx = t; idx < 2048; idx += 512)
        uo_lds[idx] = Uo[(a << 11) + idx];
    __syncthreads();

    // ---- phase X: x[b][c][r] for 2 batches per lane
    {
        const int c  = widr >> 1;
        const int r0 = (widr & 1) << 2;
        const float* nhA   = nh + (size_t)(b0 + lane) * 1024 + (size_t)c * 256;
        const float* nhB   = nhA + 64 * 1024;
        const float* ubase = sm.u + (c << 11) + r0;
        float4 accA = make_float4(0.f, 0.f, 0.f, 0.f);
        float4 accB = make_float4(0.f, 0.f, 0.f, 0.f);
        #pragma unroll 4
        for (int h = 0; h < 256; h += 4) {
            float4 vA = *(const float4*)(nhA + h);
            float4 vB = *(const float4*)(nhB + h);
            float4 u0 = *(const float4*)(ubase + ((h + 0) << 3));
            float4 u1 = *(const float4*)(ubase + ((h + 1) << 3));
            float4 u2 = *(const float4*)(ubase + ((h + 2) << 3));
            float4 u3 = *(const float4*)(ubase + ((h + 3) << 3));
            accA.x = fmaf(vA.x, u0.x, accA.x); accA.y = fmaf(vA.x, u0.y, accA.y);
            accA.z = fmaf(vA.x, u0.z, accA.z); accA.w = fmaf(vA.x, u0.w, accA.w);
            accA.x = fmaf(vA.y, u1.x, accA.x); accA.y = fmaf(vA.y, u1.y, accA.y);
            accA.z = fmaf(vA.y, u1.z, accA.z); accA.w = fmaf(vA.y, u1.w, accA.w);
            accA.x = fmaf(vA.z, u2.x, accA.x); accA.y = fmaf(vA.z, u2.y, accA.y);
            accA.z = fmaf(vA.z, u2.z, accA.z); accA.w = fmaf(vA.z, u2.w, accA.w);
            accA.x = fmaf(vA.w, u3.x, accA.x); accA.y = fmaf(vA.w, u3.y, accA.y);
            accA.z = fmaf(vA.w, u3.z, accA.z); accA.w = fmaf(vA.w, u3.w, accA.w);
            accB.x = fmaf(vB.x, u0.x, accB.x); accB.y = fmaf(vB.x, u0.y, accB.y);
            accB.z = fmaf(vB.x, u0.z, accB.z); accB.w = fmaf(vB.x, u0.w, accB.w);
            accB.x = fmaf(vB.y, u1.x, accB.x); accB.y = fmaf(vB.y, u1.y, accB.y);
            accB.z = fmaf(vB.y, u1.z, accB.z); accB.w = fmaf(vB.y, u1.w, accB.w);
            accB.x = fmaf(vB.z, u2.x, accB.x); accB.y = fmaf(vB.z, u2.y, accB.y);
            accB.z = fmaf(vB.z, u2.z, accB.z); accB.w = fmaf(vB.z, u2.w, accB.w);
            accB.x = fmaf(vB.w, u3.x, accB.x); accB.y = fmaf(vB.w, u3.y, accB.y);
            accB.z = fmaf(vB.w, u3.z, accB.z); accB.w = fmaf(vB.w, u3.w, accB.w);
        }
        const float4 bb4 = *(const float4*)&bi[((c * 4 + a) << 3) + r0];
        h_t[c * 9 + r0 + 0][lane]      = accA.x + bb4.x;
        h_t[c * 9 + r0 + 1][lane]      = accA.y + bb4.y;
        h_t[c * 9 + r0 + 2][lane]      = accA.z + bb4.z;
        h_t[c * 9 + r0 + 3][lane]      = accA.w + bb4.w;
        h_t[c * 9 + r0 + 0][lane + 64] = accB.x + bb4.x;
        h_t[c * 9 + r0 + 1][lane + 64] = accB.y + bb4.y;
        h_t[c * 9 + r0 + 2][lane + 64] = accB.z + bb4.z;
        h_t[c * 9 + r0 + 3][lane + 64] = accB.w + bb4.w;
        if (r0) {
            h_t[c * 9 + 8][lane]      = 1.0f;
            h_t[c * 9 + 8][lane + 64] = 1.0f;
        }
    }
    __syncthreads();   // all sm.u reads done before DMA overwrites the union

    // ---- phase B: wave w owns r=w; each lane accumulates 2 batches
    {
        float h0A[9], h1A[9], h2A[9], h3A[9];
        float h0B[9], h1B[9], h2B[9], h3B[9];
        #pragma unroll
        for (int q = 0; q < 9; ++q) {
            h0A[q] = h_t[q][lane];      h0B[q] = h_t[q][lane + 64];
            h1A[q] = h_t[9 + q][lane];  h1B[q] = h_t[9 + q][lane + 64];
            h2A[q] = h_t[18 + q][lane]; h2B[q] = h_t[18 + q][lane + 64];
            h3A[q] = h_t[27 + q][lane]; h3B[q] = h_t[27 + q][lane + 64];
        }
        const float* Tw = Tt + (size_t)(a * 81) * TT_ISTRIDE;
        float AA = 0.0f, AB = 0.0f;

        // prologue: stage chunk 0 into buffer 0
        {
            const float* s = Tw;
            float* d = sm.tc[0];
            GLL(s + 4 * t, d + 4 * t);
            GLL(s + 4 * (512 + t), d + 4 * (512 + t));
            if (t < CHUNK_F4 - 1024) GLL(s + 4 * (1024 + t), d + 4 * (1024 + t));
        }

        #pragma unroll 1
        for (int c = 0; c < 9; ++c) {
            if (c < 8) {
                const float* s = Tw + (size_t)(c + 1) * CHUNK_FLOATS;
                float* d = sm.tc[(c + 1) & 1];
                GLL(s + 4 * t, d + 4 * t);
                GLL(s + 4 * (512 + t), d + 4 * (512 + t));
                if (t < CHUNK_F4 - 1024) GLL(s + 4 * (1024 + t), d + 4 * (1024 + t));
                asm volatile("s_waitcnt vmcnt(3)" ::: "memory");
            } else {
                asm volatile("s_waitcnt vmcnt(0)" ::: "memory");
            }
            __builtin_amdgcn_s_barrier();          // chunk c fully landed
            asm volatile("" ::: "memory");

            const float* tcp = sm.tc[c & 1] + widr * 84;   // r = widr
            const float h0cA = h0A[c], h0cB = h0B[c];      // q0 == chunk index
            #pragma unroll 3
            for (int q1 = 0; q1 < 9; ++q1) {
                const float* tp = tcp + q1 * TT_ISTRIDE;
                float ddA = 0.0f, ddB = 0.0f;
                #pragma unroll
                for (int jt = 0; jt < 3; ++jt) {
                    float s[28];
                    #pragma unroll
                    for (int m = 0; m < 7; ++m)
                        *(float4*)(s + 4 * m) = *(const float4*)(tp + jt * 28 + 4 * m);
                    float e0A = 0.f, e1A = 0.f, e2A = 0.f;
                    float e0B = 0.f, e1B = 0.f, e2B = 0.f;
                    #pragma unroll
                    for (int m = 0; m < 9; ++m) {
                        e0A = fmaf(s[m],      h3A[m], e0A);
                        e1A = fmaf(s[9 + m],  h3A[m], e1A);
                        e2A = fmaf(s[18 + m], h3A[m], e2A);
                        e0B = fmaf(s[m],      h3B[m], e0B);
                        e1B = fmaf(s[9 + m],  h3B[m], e1B);
                        e2B = fmaf(s[18 + m], h3B[m], e2B);
                    }
                    ddA = fmaf(h2A[3 * jt], e0A, fmaf(h2A[3 * jt + 1], e1A,
                          fmaf(h2A[3 * jt + 2], e2A, ddA)));
                    ddB = fmaf(h2B[3 * jt], e0B, fmaf(h2B[3 * jt + 1], e1B,
                          fmaf(h2B[3 * jt + 2], e2B, ddB)));
                }
                AA = fmaf(h0cA * h1A[q1], ddA, AA);
                AB = fmaf(h0cB * h1B[q1], ddB, AB);
            }
            asm volatile("" ::: "memory");
            __builtin_amdgcn_s_barrier();          // buffer reuse safe next iter
        }
        ris_s[lane][widr]      = AA;
        ris_s[lane + 64][widr] = AB;
    }
    __syncthreads();

    // ---- phase C: out[b, a*256+h] = ris[b,:] . Uo[a,:,h] + bo[a,h]
    {
        const int h  = t & 255;
        const int bh = t >> 8;   // 0..1 -> 64 rows each
        const float bov = bo[(a << 8) + h];
        const float u0 = uo_lds[h],            u1 = uo_lds[256 + h];
        const float u2 = uo_lds[512 + h],      u3 = uo_lds[768 + h];
        const float u4 = uo_lds[1024 + h],     u5 = uo_lds[1280 + h];
        const float u6 = uo_lds[1536 + h],     u7 = uo_lds[1792 + h];
        float* op = out + (size_t)(b0 + (bh << 6)) * 1024 + (a << 8) + h;
        #pragma unroll 4
        for (int bb = 0; bb < 64; ++bb) {
            const int bidx = (bh << 6) + bb;
            const float4 rlo = *(const float4*)&ris_s[bidx][0];
            const float4 rhi = *(const float4*)&ris_s[bidx][4];
            float v = bov;
            v = fmaf(rlo.x, u0, v); v = fmaf(rlo.y, u1, v);
            v = fmaf(rlo.z, u2, v); v = fmaf(rlo.w, u3, v);
            v = fmaf(rhi.x, u4, v); v = fmaf(rhi.y, u5, v);
            v = fmaf(rhi.z, u6, v); v = fmaf(rhi.w, u7, v);
            op[(size_t)bb * 1024] = v;
        }
    }
}

extern "C" void kernel_launch(void* const* d_in, const int* in_sizes, int n_in,
                              void* d_out, int out_size, void* d_ws, size_t ws_size,
                              hipStream_t stream) {
    (void)in_sizes; (void)n_in; (void)out_size; (void)ws_size;
    const float* nh = (const float*)d_in[0];
    const float* U  = (const float*)d_in[1];
    const float* bi = (const float*)d_in[2];
    const float* Uo = (const float*)d_in[3];
    const float* bo = (const float*)d_in[4];
    const float* T  = (const float*)d_in[5];
    float* outp = (float*)d_out;
    float* Tt   = (float*)d_ws;   // 870,912 bytes

    t_transpose<<<(TT_ELEMS + 255) / 256, 256, 0, stream>>>(T, Tt);
    hosvd_fused<<<256, 512, 0, stream>>>(nh, U, bi, Uo, bo, Tt, outp);
}